// Round 4
// baseline (396.620 us; speedup 1.0000x reference)
//
#include <hip/hip_runtime.h>
#include <hip/hip_bf16.h>

#define NB 512
#define NS 200
#define NK 16
#define NH 256
#define INV_SQRT_H 0.0625f
#define EPS_LN 1e-12f
#define EPS_COS 1e-6f
#define KTPAD 264   // shorts per LDS row (256 + 8): spreads ds_read_b128 starts mod 8 banks

typedef __attribute__((ext_vector_type(8))) short bf16x8;
typedef __attribute__((ext_vector_type(4))) short s16x4;
typedef __attribute__((ext_vector_type(4))) float f32x4;

__device__ __forceinline__ float wred_sum(float v) {
    v += __shfl_xor(v, 1);  v += __shfl_xor(v, 2);  v += __shfl_xor(v, 4);
    v += __shfl_xor(v, 8);  v += __shfl_xor(v, 16); v += __shfl_xor(v, 32);
    return v;
}

__device__ __forceinline__ float red16(float v) {
    v += __shfl_xor(v, 1);  v += __shfl_xor(v, 2);
    v += __shfl_xor(v, 4);  v += __shfl_xor(v, 8);
    return v;
}

__device__ __forceinline__ float block_sum256(float v, float* scr) {
    v = wred_sum(v);
    int w = threadIdx.x >> 6;
    __syncthreads();
    if ((threadIdx.x & 63) == 0) scr[w] = v;
    __syncthreads();
    return scr[0] + scr[1] + scr[2] + scr[3];
}

// ---------------- Kernel 1 (merged prep): protos LN2+norm | cast W | query LN4 ----------------
__global__ __launch_bounds__(256) void k_prep(
        const float* __restrict__ prot, const float* __restrict__ w2, const float* __restrict__ b2,
        const float* __restrict__ w_weight, __hip_bfloat16* __restrict__ w_bf,
        const float* __restrict__ z, const float* __restrict__ b_prime,
        const float* __restrict__ alphas, const float* __restrict__ w4, const float* __restrict__ b4,
        float* __restrict__ pn_div, float* __restrict__ q) {
    __shared__ float scr[4];
    int t = threadIdx.x;
    int bid = blockIdx.x;
    if (bid == 0) {
        // 16-lane group per prototype: no block barriers, 3 short red16 chains
        int c = t & 15, k = t >> 4;
        int h0 = c * 4;
        f32x4 x[4];
        float sm = 0.f, sq = 0.f;
#pragma unroll
        for (int j = 0; j < 4; ++j) {
            x[j] = *reinterpret_cast<const f32x4*>(prot + k * NH + h0 + 64 * j);
#pragma unroll
            for (int i = 0; i < 4; ++i) { sm += x[j][i]; sq += x[j][i] * x[j][i]; }
        }
        sm = red16(sm); sq = red16(sq);
        float u = sm * (1.f / NH);
        float var = sq * (1.f / NH) - u * u;
        float rstd = rsqrtf(var + EPS_LN);
        f32x4 pn[4];
        float nsq = 0.f;
#pragma unroll
        for (int j = 0; j < 4; ++j) {
            f32x4 wv = *reinterpret_cast<const f32x4*>(w2 + h0 + 64 * j);
            f32x4 bv = *reinterpret_cast<const f32x4*>(b2 + h0 + 64 * j);
#pragma unroll
            for (int i = 0; i < 4; ++i) {
                pn[j][i] = wv[i] * (x[j][i] - u) * rstd + bv[i];
                nsq += pn[j][i] * pn[j][i];
            }
        }
        nsq = red16(nsq);
        float pinv = 1.f / fmaxf(sqrtf(nsq), EPS_COS);
#pragma unroll
        for (int j = 0; j < 4; ++j) {
            f32x4 o = pn[j] * pinv;
            *reinterpret_cast<f32x4*>(pn_div + k * NH + h0 + 64 * j) = o;
        }
    } else if (bid <= 64) {
        int i = ((bid - 1) * 256 + t) * 4;
        f32x4 w = *reinterpret_cast<const f32x4*>(w_weight + i);
        union { s16x4 v; __hip_bfloat16 h[4]; } u;
#pragma unroll
        for (int j = 0; j < 4; ++j) u.h[j] = __float2bfloat16(w[j]);
        *reinterpret_cast<s16x4*>(w_bf + i) = u.v;
    } else {
        int b = bid - 65;
        float x = b_prime[t] + alphas[(NS - 1) * NH + t] + z[((size_t)b * NS + (NS - 1)) * NH + t];
        float u = block_sum256(x, scr) * (1.f / NH);
        float d = x - u;
        float var = block_sum256(d * d, scr) * (1.f / NH);
        q[b * NH + t] = w4[t] * d * rsqrtf(var + EPS_LN) + b4[t];
    }
}

// ---------------- Kernel 2 (fused): row pass -> kt in LDS -> MFMA GEMM -> scores ----------------
// Block = 64 rows. Phase 1: 16 lanes/row, 4 rows/thread-group (unroll 1 to cap VGPR).
// Phase 2: 4 waves x 64 cols MFMA, A-fragments from LDS (padded stride, conflict-free).
__global__ __launch_bounds__(256) void k_rows_gemm(
        const float* __restrict__ z, const float* __restrict__ pn_div,
        const float* __restrict__ ln1w, const float* __restrict__ ln1b,
        const float* __restrict__ ln3w, const float* __restrict__ ln3b,
        const float* __restrict__ alphas, const float* __restrict__ q,
        const __hip_bfloat16* __restrict__ w_bf, const float* __restrict__ w_bias,
        float* __restrict__ p_k_i, float* __restrict__ scores) {
    __shared__ __hip_bfloat16 kt_lds[64 * KTPAD];   // 33.8 KB
    __shared__ float ktq_lds[64];
    __shared__ float sc[4][64];

    int tid = threadIdx.x;
    int c   = tid & 15;
    int grp = tid >> 4;
    int row0 = blockIdx.x * 64;
    int h0 = c * 4;

    // ---------------- Phase 1: per-row pass ----------------
#pragma unroll 1
    for (int jr = 0; jr < 4; ++jr) {
        int rl  = grp + 16 * jr;          // local row 0..63
        int row = row0 + rl;
        int s   = row % NS;
        int b   = row / NS;
        size_t base = (size_t)row * NH;

        f32x4 zv[4];
#pragma unroll
        for (int j = 0; j < 4; ++j)
            zv[j] = *reinterpret_cast<const f32x4*>(z + base + h0 + 64 * j);

        // LN1
        float sm = 0.f, sq = 0.f;
#pragma unroll
        for (int j = 0; j < 4; ++j)
#pragma unroll
            for (int i = 0; i < 4; ++i) { sm += zv[j][i]; sq += zv[j][i] * zv[j][i]; }
        sm = red16(sm); sq = red16(sq);
        float u    = sm * (1.f / NH);
        float var  = sq * (1.f / NH) - u * u;
        float rstd = rsqrtf(var + EPS_LN);

        f32x4 zn[4];
        float nsq = 0.f;
#pragma unroll
        for (int j = 0; j < 4; ++j) {
            f32x4 w1 = *reinterpret_cast<const f32x4*>(ln1w + h0 + 64 * j);
            f32x4 b1 = *reinterpret_cast<const f32x4*>(ln1b + h0 + 64 * j);
#pragma unroll
            for (int i = 0; i < 4; ++i) {
                zn[j][i] = w1[i] * (zv[j][i] - u) * rstd + b1[i];
                nsq += zn[j][i] * zn[j][i];
            }
        }
        nsq = red16(nsq);
        float inv_zn = 1.f / fmaxf(sqrtf(nsq), EPS_COS);

        // 16 prototype dot products
        float acc[NK];
#pragma unroll
        for (int k = 0; k < NK; ++k) {
            float a = 0.f;
#pragma unroll
            for (int j = 0; j < 4; ++j) {
                f32x4 p = *reinterpret_cast<const f32x4*>(pn_div + k * NH + h0 + 64 * j);
                a += zn[j][0]*p[0] + zn[j][1]*p[1] + zn[j][2]*p[2] + zn[j][3]*p[3];
            }
            acc[k] = a;
        }
        // packed butterfly within 16 lanes: lane c ends with total for k = c
#pragma unroll
        for (int r = 0; r < 4; ++r) {
            int m = 1 << r;
            int n = NK >> r;
            bool hi = (c & m) != 0;
#pragma unroll
            for (int i = 0; i < 8; ++i) {
                if (i < n / 2) {
                    float a = acc[2 * i], bb = acc[2 * i + 1];
                    float x = hi ? a : bb;
                    float y = __shfl_xor(x, m);
                    acc[i] = (hi ? bb : a) + y;
                }
            }
        }

        // softmax over 16-lane group
        float logit = acc[0] * inv_zn * INV_SQRT_H;
        float mx = logit;
        mx = fmaxf(mx, __shfl_xor(mx, 1)); mx = fmaxf(mx, __shfl_xor(mx, 2));
        mx = fmaxf(mx, __shfl_xor(mx, 4)); mx = fmaxf(mx, __shfl_xor(mx, 8));
        float e = __expf(logit - mx);
        float se = e;
        se += __shfl_xor(se, 1); se += __shfl_xor(se, 2);
        se += __shfl_xor(se, 4); se += __shfl_xor(se, 8);
        p_k_i[(size_t)row * NK + c] = e / se;

        // keys_tilde = LN3(z + alphas[s]) -> LDS (bf16), plus kt . q
        f32x4 xv[4];
        sm = 0.f; sq = 0.f;
#pragma unroll
        for (int j = 0; j < 4; ++j) {
            f32x4 av = *reinterpret_cast<const f32x4*>(alphas + s * NH + h0 + 64 * j);
            xv[j] = zv[j] + av;
#pragma unroll
            for (int i = 0; i < 4; ++i) { sm += xv[j][i]; sq += xv[j][i] * xv[j][i]; }
        }
        sm = red16(sm); sq = red16(sq);
        float u3 = sm * (1.f / NH);
        float v3 = sq * (1.f / NH) - u3 * u3;
        float r3 = rsqrtf(v3 + EPS_LN);

        float ktq = 0.f;
#pragma unroll
        for (int j = 0; j < 4; ++j) {
            f32x4 w3 = *reinterpret_cast<const f32x4*>(ln3w + h0 + 64 * j);
            f32x4 b3 = *reinterpret_cast<const f32x4*>(ln3b + h0 + 64 * j);
            f32x4 qv = *reinterpret_cast<const f32x4*>(q + b * NH + h0 + 64 * j);
            union { s16x4 v; __hip_bfloat16 h[4]; } kv;
#pragma unroll
            for (int i = 0; i < 4; ++i) {
                float key = w3[i] * (xv[j][i] - u3) * r3 + b3[i];
                kv.h[i] = __float2bfloat16(key);
                ktq += key * qv[i];
            }
            *reinterpret_cast<s16x4*>(&kt_lds[rl * KTPAD + h0 + 64 * j]) = kv.v;
        }
        ktq = red16(ktq);
        if (c == 0) ktq_lds[rl] = ktq;
    }
    __syncthreads();

    // ---------------- Phase 2: MFMA kt @ W^T + relu.q epilogue ----------------
    int wave = tid >> 6, lane = tid & 63;
    int g = lane >> 4, cc = lane & 15;
    int n_base = wave * 64;

    f32x4 acc[4][4];
#pragma unroll
    for (int mf = 0; mf < 4; ++mf)
#pragma unroll
        for (int nf = 0; nf < 4; ++nf) { f32x4 zz = {0.f, 0.f, 0.f, 0.f}; acc[mf][nf] = zz; }

#pragma unroll
    for (int ks = 0; ks < 8; ++ks) {
        bf16x8 a[4], bb[4];
#pragma unroll
        for (int mf = 0; mf < 4; ++mf)
            a[mf] = *reinterpret_cast<const bf16x8*>(&kt_lds[(mf * 16 + cc) * KTPAD + ks * 32 + g * 8]);
#pragma unroll
        for (int nf = 0; nf < 4; ++nf)
            bb[nf] = *reinterpret_cast<const bf16x8*>(
                w_bf + (size_t)(n_base + nf * 16 + cc) * NH + ks * 32 + g * 8);
#pragma unroll
        for (int mf = 0; mf < 4; ++mf)
#pragma unroll
            for (int nf = 0; nf < 4; ++nf)
                acc[mf][nf] = __builtin_amdgcn_mfma_f32_16x16x32_bf16(a[mf], bb[nf], acc[mf][nf], 0, 0, 0);
    }

    // epilogue: relu(u + bias) . q
#pragma unroll
    for (int mf = 0; mf < 4; ++mf) {
#pragma unroll
        for (int r = 0; r < 4; ++r) {
            int m = mf * 16 + g * 4 + r;
            int row = row0 + m;
            int bb2 = row / NS;
            float partial = 0.f;
#pragma unroll
            for (int nf = 0; nf < 4; ++nf) {
                int n = n_base + nf * 16 + cc;
                float uval = acc[mf][nf][r] + w_bias[n];
                partial += fmaxf(uval, 0.f) * q[bb2 * NH + n];
            }
            partial += __shfl_xor(partial, 1, 16);
            partial += __shfl_xor(partial, 2, 16);
            partial += __shfl_xor(partial, 4, 16);
            partial += __shfl_xor(partial, 8, 16);
            if (cc == 0) sc[wave][m] = partial;
        }
    }
    __syncthreads();
    if (tid < 64)
        scores[row0 + tid] = ktq_lds[tid] + sc[0][tid] + sc[1][tid] + sc[2][tid] + sc[3][tid];
}

// ---------------- Kernel 3: softmax over S, aggregate (waves split K), LN5 ----------------
__global__ __launch_bounds__(256) void k_final(
        const float* __restrict__ z, const float* __restrict__ scores,
        const float* __restrict__ p_k_i,
        const float* __restrict__ beta_in, const float* __restrict__ beta_lb,
        const int* __restrict__ flag,
        const float* __restrict__ ln5w, const float* __restrict__ ln5b,
        float* __restrict__ out) {
    __shared__ float p_i[NS];
    __shared__ f32x4 attn4[NS * 4];
    int tid = threadIdx.x, lane = tid & 63, wave = tid >> 6;
    int b = blockIdx.x;

    if (wave == 0) {
        float l[4]; float mx = -1e30f;
#pragma unroll
        for (int j = 0; j < 4; ++j) {
            int s = lane + 64 * j;
            l[j] = (s < NS) ? scores[b * NS + s] * INV_SQRT_H : -1e30f;
            mx = fmaxf(mx, l[j]);
        }
#pragma unroll
        for (int m = 1; m < 64; m <<= 1) mx = fmaxf(mx, __shfl_xor(mx, m));
        float ev[4]; float se = 0.f;
#pragma unroll
        for (int j = 0; j < 4; ++j) {
            int s = lane + 64 * j;
            ev[j] = (s < NS) ? __expf(l[j] - mx) : 0.f;
            se += ev[j];
        }
        se = wred_sum(se);
        float inv = 1.f / se;
#pragma unroll
        for (int j = 0; j < 4; ++j) {
            int s = lane + 64 * j;
            if (s < NS) p_i[s] = ev[j] * inv;
        }
    }
    __syncthreads();
    for (int idx = tid; idx < NS * 4; idx += 256) {
        f32x4 pk = *reinterpret_cast<const f32x4*>(p_k_i + (size_t)b * NS * NK + idx * 4);
        attn4[idx] = pk * p_i[idx >> 2];
    }
    __syncthreads();

    const float* beta = (*flag) ? beta_in : beta_lb;
    int k0 = wave * 4;
    int h0 = lane * 4;
    f32x4 acc[4];
#pragma unroll
    for (int kk = 0; kk < 4; ++kk)
        acc[kk] = *reinterpret_cast<const f32x4*>(beta + (k0 + kk) * NH + h0);

    const float* zb = z + (size_t)b * NS * NH + h0;
    for (int s = 0; s < NS; s += 4) {
        f32x4 zv0 = *reinterpret_cast<const f32x4*>(zb + (s + 0) * NH);
        f32x4 zv1 = *reinterpret_cast<const f32x4*>(zb + (s + 1) * NH);
        f32x4 zv2 = *reinterpret_cast<const f32x4*>(zb + (s + 2) * NH);
        f32x4 zv3 = *reinterpret_cast<const f32x4*>(zb + (s + 3) * NH);
        f32x4 at0 = attn4[(s + 0) * 4 + wave];
        f32x4 at1 = attn4[(s + 1) * 4 + wave];
        f32x4 at2 = attn4[(s + 2) * 4 + wave];
        f32x4 at3 = attn4[(s + 3) * 4 + wave];
#pragma unroll
        for (int kk = 0; kk < 4; ++kk)
            acc[kk] += at0[kk] * zv0 + at1[kk] * zv1 + at2[kk] * zv2 + at3[kk] * zv3;
    }

    f32x4 w5 = *reinterpret_cast<const f32x4*>(ln5w + h0);
    f32x4 b5 = *reinterpret_cast<const f32x4*>(ln5b + h0);
#pragma unroll
    for (int kk = 0; kk < 4; ++kk) {
        float sm = acc[kk][0] + acc[kk][1] + acc[kk][2] + acc[kk][3];
        float sq = acc[kk][0]*acc[kk][0] + acc[kk][1]*acc[kk][1]
                 + acc[kk][2]*acc[kk][2] + acc[kk][3]*acc[kk][3];
        sm = wred_sum(sm); sq = wred_sum(sq);
        float u = sm * (1.f / NH);
        float var = sq * (1.f / NH) - u * u;
        float rstd = rsqrtf(var + EPS_LN);
        f32x4 o;
#pragma unroll
        for (int j = 0; j < 4; ++j) o[j] = w5[j] * (acc[kk][j] - u) * rstd + b5[j];
        *reinterpret_cast<f32x4*>(out + ((size_t)b * NK + k0 + kk) * NH + h0) = o;
    }
}

extern "C" void kernel_launch(void* const* d_in, const int* in_sizes, int n_in,
                              void* d_out, int out_size, void* d_ws, size_t ws_size,
                              hipStream_t stream) {
    const float* z        = (const float*)d_in[0];
    const float* prot     = (const float*)d_in[1];
    const float* ln1w     = (const float*)d_in[2];
    const float* ln1b     = (const float*)d_in[3];
    const float* ln2w     = (const float*)d_in[4];
    const float* ln2b     = (const float*)d_in[5];
    const float* ln3w     = (const float*)d_in[6];
    const float* ln3b     = (const float*)d_in[7];
    const float* ln4w     = (const float*)d_in[8];
    const float* ln4b     = (const float*)d_in[9];
    const float* ln5w     = (const float*)d_in[10];
    const float* ln5b     = (const float*)d_in[11];
    const float* w_weight = (const float*)d_in[12];
    const float* w_bias   = (const float*)d_in[13];
    const float* b_prime  = (const float*)d_in[14];
    const float* alphas   = (const float*)d_in[15];
    const float* beta_in  = (const float*)d_in[16];
    const float* beta_lb  = (const float*)d_in[17];
    const int*   flag     = (const int*)d_in[18];
    float* out = (float*)d_out;

    char* ws = (char*)d_ws;
    float*          pn_div = (float*)(ws);                       // 16 KB
    float*          q      = (float*)(ws + 16384);               // 512 KB
    __hip_bfloat16* w_bf   = (__hip_bfloat16*)(ws + 540672);     // 128 KB
    float*          p_k_i  = (float*)(ws + 671744);              // 6.55 MB
    float*          scores = (float*)(ws + 7225344);             // 410 KB

    k_prep<<<577, 256, 0, stream>>>(prot, ln2w, ln2b, w_weight, w_bf,
                                    z, b_prime, alphas, ln4w, ln4b, pn_div, q);
    k_rows_gemm<<<NB * NS / 64, 256, 0, stream>>>(z, pn_div, ln1w, ln1b, ln3w, ln3b,
                                                  alphas, q, w_bf, w_bias, p_k_i, scores);
    k_final<<<NB, 256, 0, stream>>>(z, scores, p_k_i, beta_in, beta_lb, flag, ln5w, ln5b, out);
}

// Round 6
// 316.973 us; speedup vs baseline: 1.2513x; 1.2513x over previous
//
#include <hip/hip_runtime.h>
#include <hip/hip_bf16.h>

#define NB 512
#define NS 200
#define NK 16
#define NH 256
#define INV_SQRT_H 0.0625f
#define EPS_LN 1e-12f
#define EPS_COS 1e-6f
#define KTPAD 264   // shorts per LDS row: ds_read_b128 starts spread ~2-way (free, m136)

typedef __attribute__((ext_vector_type(8))) short bf16x8;
typedef __attribute__((ext_vector_type(4))) short s16x4;
typedef __attribute__((ext_vector_type(4))) float f32x4;

__device__ __forceinline__ float wred_sum(float v) {
    v += __shfl_xor(v, 1);  v += __shfl_xor(v, 2);  v += __shfl_xor(v, 4);
    v += __shfl_xor(v, 8);  v += __shfl_xor(v, 16); v += __shfl_xor(v, 32);
    return v;
}

__device__ __forceinline__ float red16(float v) {
    v += __shfl_xor(v, 1);  v += __shfl_xor(v, 2);
    v += __shfl_xor(v, 4);  v += __shfl_xor(v, 8);
    return v;
}

__device__ __forceinline__ float red32(float v) {
    v += __shfl_xor(v, 1);  v += __shfl_xor(v, 2);  v += __shfl_xor(v, 4);
    v += __shfl_xor(v, 8);  v += __shfl_xor(v, 16);
    return v;
}

__device__ __forceinline__ float block_sum256(float v, float* scr) {
    v = wred_sum(v);
    int w = threadIdx.x >> 6;
    __syncthreads();
    if ((threadIdx.x & 63) == 0) scr[w] = v;
    __syncthreads();
    return scr[0] + scr[1] + scr[2] + scr[3];
}

// ---------------- Kernel 1 (merged prep): protos LN2+norm | cast W | query LN4 ----------------
__global__ __launch_bounds__(256) void k_prep(
        const float* __restrict__ prot, const float* __restrict__ w2, const float* __restrict__ b2,
        const float* __restrict__ w_weight, __hip_bfloat16* __restrict__ w_bf,
        const float* __restrict__ z, const float* __restrict__ b_prime,
        const float* __restrict__ alphas, const float* __restrict__ w4, const float* __restrict__ b4,
        float* __restrict__ pn_div, float* __restrict__ q) {
    __shared__ float scr[4];
    int t = threadIdx.x;
    int bid = blockIdx.x;
    if (bid == 0) {
        int c = t & 15, k = t >> 4;
        int h0 = c * 4;
        f32x4 x[4];
        float sm = 0.f, sq = 0.f;
#pragma unroll
        for (int j = 0; j < 4; ++j) {
            x[j] = *reinterpret_cast<const f32x4*>(prot + k * NH + h0 + 64 * j);
#pragma unroll
            for (int i = 0; i < 4; ++i) { sm += x[j][i]; sq += x[j][i] * x[j][i]; }
        }
        sm = red16(sm); sq = red16(sq);
        float u = sm * (1.f / NH);
        float var = sq * (1.f / NH) - u * u;
        float rstd = rsqrtf(var + EPS_LN);
        f32x4 pn[4];
        float nsq = 0.f;
#pragma unroll
        for (int j = 0; j < 4; ++j) {
            f32x4 wv = *reinterpret_cast<const f32x4*>(w2 + h0 + 64 * j);
            f32x4 bv = *reinterpret_cast<const f32x4*>(b2 + h0 + 64 * j);
#pragma unroll
            for (int i = 0; i < 4; ++i) {
                pn[j][i] = wv[i] * (x[j][i] - u) * rstd + bv[i];
                nsq += pn[j][i] * pn[j][i];
            }
        }
        nsq = red16(nsq);
        float pinv = 1.f / fmaxf(sqrtf(nsq), EPS_COS);
#pragma unroll
        for (int j = 0; j < 4; ++j) {
            f32x4 o = pn[j] * pinv;
            *reinterpret_cast<f32x4*>(pn_div + k * NH + h0 + 64 * j) = o;
        }
    } else if (bid <= 64) {
        int i = ((bid - 1) * 256 + t) * 4;
        f32x4 w = *reinterpret_cast<const f32x4*>(w_weight + i);
        union { s16x4 v; __hip_bfloat16 h[4]; } u;
#pragma unroll
        for (int j = 0; j < 4; ++j) u.h[j] = __float2bfloat16(w[j]);
        *reinterpret_cast<s16x4*>(w_bf + i) = u.v;
    } else {
        int b = bid - 65;
        float x = b_prime[t] + alphas[(NS - 1) * NH + t] + z[((size_t)b * NS + (NS - 1)) * NH + t];
        float u = block_sum256(x, scr) * (1.f / NH);
        float d = x - u;
        float var = block_sum256(d * d, scr) * (1.f / NH);
        q[b * NH + t] = w4[t] * d * rsqrtf(var + EPS_LN) + b4[t];
    }
}

// ---------------- Kernel 2: per-row pass, 32 lanes/row (2 rows/wave, 8 rows/block) ----------------
__global__ __launch_bounds__(256) void k_rows(
        const float* __restrict__ z, const float* __restrict__ pn_div,
        const float* __restrict__ ln1w, const float* __restrict__ ln1b,
        const float* __restrict__ ln3w, const float* __restrict__ ln3b,
        const float* __restrict__ alphas, const float* __restrict__ q,
        float* __restrict__ p_k_i, __hip_bfloat16* __restrict__ kt,
        float* __restrict__ scores) {
    int tid = threadIdx.x;
    int c   = tid & 31;                 // lane within 32-group
    int row = blockIdx.x * 8 + (tid >> 5);
    int s   = row % NS;
    int b   = row / NS;
    size_t base = (size_t)row * NH;
    int h0 = c * 8;                     // owns h0..h0+7

    // ---- LN1 (zv live only through zn computation) ----
    f32x4 zv0 = *reinterpret_cast<const f32x4*>(z + base + h0);
    f32x4 zv1 = *reinterpret_cast<const f32x4*>(z + base + h0 + 4);
    float sm = 0.f, sq = 0.f;
#pragma unroll
    for (int i = 0; i < 4; ++i) { sm += zv0[i] + zv1[i]; sq += zv0[i]*zv0[i] + zv1[i]*zv1[i]; }
    sm = red32(sm); sq = red32(sq);
    float u    = sm * (1.f / NH);
    float var  = sq * (1.f / NH) - u * u;
    float rstd = rsqrtf(var + EPS_LN);

    f32x4 zn0, zn1;
    {
        f32x4 w1a = *reinterpret_cast<const f32x4*>(ln1w + h0);
        f32x4 w1b = *reinterpret_cast<const f32x4*>(ln1w + h0 + 4);
        f32x4 b1a = *reinterpret_cast<const f32x4*>(ln1b + h0);
        f32x4 b1b = *reinterpret_cast<const f32x4*>(ln1b + h0 + 4);
        float nsq = 0.f;
#pragma unroll
        for (int i = 0; i < 4; ++i) {
            zn0[i] = w1a[i] * (zv0[i] - u) * rstd + b1a[i];
            zn1[i] = w1b[i] * (zv1[i] - u) * rstd + b1b[i];
            nsq += zn0[i]*zn0[i] + zn1[i]*zn1[i];
        }
        nsq = red32(nsq);
        float inv_zn = 1.f / fmaxf(sqrtf(nsq), EPS_COS);
        sm = inv_zn;   // reuse reg
    }
    float inv_zn = sm;

    // ---- 16 prototype dot products ----
    float acc[NK];
#pragma unroll
    for (int k = 0; k < NK; ++k) {
        f32x4 pa = *reinterpret_cast<const f32x4*>(pn_div + k * NH + h0);
        f32x4 pb = *reinterpret_cast<const f32x4*>(pn_div + k * NH + h0 + 4);
        acc[k] = zn0[0]*pa[0] + zn0[1]*pa[1] + zn0[2]*pa[2] + zn0[3]*pa[3]
               + zn1[0]*pb[0] + zn1[1]*pb[1] + zn1[2]*pb[2] + zn1[3]*pb[3];
    }
    // packed butterfly over bits 0..3: lane c ends with total (within 16-subgroup) for k = c&15
#pragma unroll
    for (int r = 0; r < 4; ++r) {
        int m = 1 << r;
        int n = NK >> r;
        bool hi = (c & m) != 0;
#pragma unroll
        for (int i = 0; i < 8; ++i) {
            if (i < n / 2) {
                float a = acc[2 * i], bb = acc[2 * i + 1];
                float x = hi ? a : bb;
                float y = __shfl_xor(x, m);
                acc[i] = (hi ? bb : a) + y;
            }
        }
    }
    acc[0] += __shfl_xor(acc[0], 16);   // fold the two 16-subgroups

    // ---- softmax over 16-lane group ----
    float logit = acc[0] * inv_zn * INV_SQRT_H;
    float mx = logit;
    mx = fmaxf(mx, __shfl_xor(mx, 1)); mx = fmaxf(mx, __shfl_xor(mx, 2));
    mx = fmaxf(mx, __shfl_xor(mx, 4)); mx = fmaxf(mx, __shfl_xor(mx, 8));
    float e = __expf(logit - mx);
    float se = e;
    se += __shfl_xor(se, 1); se += __shfl_xor(se, 2);
    se += __shfl_xor(se, 4); se += __shfl_xor(se, 8);
    if (c < NK) p_k_i[(size_t)row * NK + c] = e / se;

    // ---- keys_tilde = LN3(z + alphas[s]) -> kt(bf16) + kt.q  (z reloaded, L1/L2-hot) ----
    f32x4 xv0, xv1;
    {
        f32x4 za = *reinterpret_cast<const f32x4*>(z + base + h0);
        f32x4 zb = *reinterpret_cast<const f32x4*>(z + base + h0 + 4);
        f32x4 aa = *reinterpret_cast<const f32x4*>(alphas + s * NH + h0);
        f32x4 ab = *reinterpret_cast<const f32x4*>(alphas + s * NH + h0 + 4);
        xv0 = za + aa; xv1 = zb + ab;
    }
    float sm3 = 0.f, sq3 = 0.f;
#pragma unroll
    for (int i = 0; i < 4; ++i) { sm3 += xv0[i] + xv1[i]; sq3 += xv0[i]*xv0[i] + xv1[i]*xv1[i]; }
    sm3 = red32(sm3); sq3 = red32(sq3);
    float u3 = sm3 * (1.f / NH);
    float v3 = sq3 * (1.f / NH) - u3 * u3;
    float r3 = rsqrtf(v3 + EPS_LN);

    float ktq = 0.f;
    union { bf16x8 v; __hip_bfloat16 h[8]; } kv;
    {
        f32x4 w3a = *reinterpret_cast<const f32x4*>(ln3w + h0);
        f32x4 w3b = *reinterpret_cast<const f32x4*>(ln3w + h0 + 4);
        f32x4 b3a = *reinterpret_cast<const f32x4*>(ln3b + h0);
        f32x4 b3b = *reinterpret_cast<const f32x4*>(ln3b + h0 + 4);
        f32x4 qa  = *reinterpret_cast<const f32x4*>(q + b * NH + h0);
        f32x4 qb  = *reinterpret_cast<const f32x4*>(q + b * NH + h0 + 4);
#pragma unroll
        for (int i = 0; i < 4; ++i) {
            float k0 = w3a[i] * (xv0[i] - u3) * r3 + b3a[i];
            float k1 = w3b[i] * (xv1[i] - u3) * r3 + b3b[i];
            kv.h[i]     = __float2bfloat16(k0);
            kv.h[i + 4] = __float2bfloat16(k1);
            ktq += k0 * qa[i] + k1 * qb[i];
        }
    }
    *reinterpret_cast<bf16x8*>(kt + base + h0) = kv.v;   // 16B coalesced
    ktq = red32(ktq);
    if (c == 0) scores[row] = ktq;
}

// ---------------- Kernel 3: MFMA GEMM kt@W^T (A staged in LDS) + relu.q ----------------
__global__ __launch_bounds__(256) void k_gemm_scores(
        const __hip_bfloat16* __restrict__ kt, const __hip_bfloat16* __restrict__ w_bf,
        const float* __restrict__ w_bias, const float* __restrict__ q,
        float* __restrict__ scores) {
    __shared__ __hip_bfloat16 kt_lds[64 * KTPAD];   // 33.8 KB
    __shared__ float sc[4][64];
    int tid = threadIdx.x, wave = tid >> 6, lane = tid & 63;
    int g = lane >> 4, cc = lane & 15;
    int row0 = blockIdx.x * 64;
    int n_base = wave * 64;

    // stage A tile: coalesced global, ~2-way LDS writes (free)
#pragma unroll
    for (int u = 0; u < 8; ++u) {
        int ci = u * 256 + tid;
        bf16x8 v = *reinterpret_cast<const bf16x8*>(kt + (size_t)row0 * NH + ci * 8);
        int r = ci >> 5;
        int col = (ci & 31) * 8;
        *reinterpret_cast<bf16x8*>(&kt_lds[r * KTPAD + col]) = v;
    }
    __syncthreads();

    f32x4 acc[4][4];
#pragma unroll
    for (int mf = 0; mf < 4; ++mf)
#pragma unroll
        for (int nf = 0; nf < 4; ++nf) { f32x4 zz = {0.f, 0.f, 0.f, 0.f}; acc[mf][nf] = zz; }

#pragma unroll
    for (int ks = 0; ks < 8; ++ks) {
        bf16x8 a[4], bb[4];
#pragma unroll
        for (int mf = 0; mf < 4; ++mf)
            a[mf] = *reinterpret_cast<const bf16x8*>(&kt_lds[(mf * 16 + cc) * KTPAD + ks * 32 + g * 8]);
#pragma unroll
        for (int nf = 0; nf < 4; ++nf)
            bb[nf] = *reinterpret_cast<const bf16x8*>(
                w_bf + (size_t)(n_base + nf * 16 + cc) * NH + ks * 32 + g * 8);
#pragma unroll
        for (int mf = 0; mf < 4; ++mf)
#pragma unroll
            for (int nf = 0; nf < 4; ++nf)
                acc[mf][nf] = __builtin_amdgcn_mfma_f32_16x16x32_bf16(a[mf], bb[nf], acc[mf][nf], 0, 0, 0);
    }

    // hoisted q values for this wave's 4 n-columns, both possible b's in the 64-row span
    int b_lo = row0 / NS, b_hi = (row0 + 63) / NS;
    float q_lo[4], q_hi[4];
#pragma unroll
    for (int nf = 0; nf < 4; ++nf) {
        int n = n_base + nf * 16 + cc;
        q_lo[nf] = q[b_lo * NH + n];
        q_hi[nf] = q[b_hi * NH + n];
    }

#pragma unroll
    for (int mf = 0; mf < 4; ++mf) {
#pragma unroll
        for (int r = 0; r < 4; ++r) {
            int m = mf * 16 + g * 4 + r;
            int row = row0 + m;
            bool hi = (row / NS) != b_lo;
            float partial = 0.f;
#pragma unroll
            for (int nf = 0; nf < 4; ++nf) {
                int n = n_base + nf * 16 + cc;
                float uval = acc[mf][nf][r] + w_bias[n];
                partial += fmaxf(uval, 0.f) * (hi ? q_hi[nf] : q_lo[nf]);
            }
            partial += __shfl_xor(partial, 1, 16);
            partial += __shfl_xor(partial, 2, 16);
            partial += __shfl_xor(partial, 4, 16);
            partial += __shfl_xor(partial, 8, 16);
            if (cc == 0) sc[wave][m] = partial;
        }
    }
    __syncthreads();
    if (tid < 64)
        scores[row0 + tid] += sc[0][tid] + sc[1][tid] + sc[2][tid] + sc[3][tid];
}

// ---------------- Kernel 4: softmax over S, aggregate (8 waves: 4 k-groups x 2 s-halves), LN5 ----------------
__global__ __launch_bounds__(512) void k_final(
        const float* __restrict__ z, const float* __restrict__ scores,
        const float* __restrict__ p_k_i,
        const float* __restrict__ beta_in, const float* __restrict__ beta_lb,
        const int* __restrict__ flag,
        const float* __restrict__ ln5w, const float* __restrict__ ln5b,
        float* __restrict__ out) {
    __shared__ float p_i[NS];
    __shared__ f32x4 attn4[NS * 4];     // 12.8 KB
    __shared__ f32x4 encp[NK][64];      // 16 KB: partial enc from s-half 1
    int tid = threadIdx.x, lane = tid & 63, wave = tid >> 6;
    int b = blockIdx.x;

    if (wave == 0) {
        float l[4]; float mx = -1e30f;
#pragma unroll
        for (int j = 0; j < 4; ++j) {
            int s = lane + 64 * j;
            l[j] = (s < NS) ? scores[b * NS + s] * INV_SQRT_H : -1e30f;
            mx = fmaxf(mx, l[j]);
        }
#pragma unroll
        for (int m = 1; m < 64; m <<= 1) mx = fmaxf(mx, __shfl_xor(mx, m));
        float ev[4]; float se = 0.f;
#pragma unroll
        for (int j = 0; j < 4; ++j) {
            int s = lane + 64 * j;
            ev[j] = (s < NS) ? __expf(l[j] - mx) : 0.f;
            se += ev[j];
        }
        se = wred_sum(se);
        float inv = 1.f / se;
#pragma unroll
        for (int j = 0; j < 4; ++j) {
            int s = lane + 64 * j;
            if (s < NS) p_i[s] = ev[j] * inv;
        }
    }
    __syncthreads();
    for (int idx = tid; idx < NS * 4; idx += 512) {
        f32x4 pk = *reinterpret_cast<const f32x4*>(p_k_i + (size_t)b * NS * NK + idx * 4);
        attn4[idx] = pk * p_i[idx >> 2];
    }
    __syncthreads();

    const float* beta = (*flag) ? beta_in : beta_lb;
    int kg = wave & 3;                  // k-group
    int sh = wave >> 2;                 // s-half
    int k0 = kg * 4;
    int h0 = lane * 4;
    f32x4 acc[4];
#pragma unroll
    for (int kk = 0; kk < 4; ++kk) {
        if (sh == 0)
            acc[kk] = *reinterpret_cast<const f32x4*>(beta + (k0 + kk) * NH + h0);
        else
            { f32x4 zz = {0.f,0.f,0.f,0.f}; acc[kk] = zz; }
    }

    const float* zb = z + (size_t)b * NS * NH + h0;
    int s0 = sh * 100;
    for (int s = s0; s < s0 + 100; s += 4) {
        f32x4 zv0 = *reinterpret_cast<const f32x4*>(zb + (s + 0) * NH);
        f32x4 zv1 = *reinterpret_cast<const f32x4*>(zb + (s + 1) * NH);
        f32x4 zv2 = *reinterpret_cast<const f32x4*>(zb + (s + 2) * NH);
        f32x4 zv3 = *reinterpret_cast<const f32x4*>(zb + (s + 3) * NH);
        f32x4 at0 = attn4[(s + 0) * 4 + kg];
        f32x4 at1 = attn4[(s + 1) * 4 + kg];
        f32x4 at2 = attn4[(s + 2) * 4 + kg];
        f32x4 at3 = attn4[(s + 3) * 4 + kg];
#pragma unroll
        for (int kk = 0; kk < 4; ++kk)
            acc[kk] += at0[kk] * zv0 + at1[kk] * zv1 + at2[kk] * zv2 + at3[kk] * zv3;
    }

    if (sh == 1) {
#pragma unroll
        for (int kk = 0; kk < 4; ++kk) encp[k0 + kk][lane] = acc[kk];
    }
    __syncthreads();
    if (sh == 0) {
        f32x4 w5 = *reinterpret_cast<const f32x4*>(ln5w + h0);
        f32x4 b5 = *reinterpret_cast<const f32x4*>(ln5b + h0);
#pragma unroll
        for (int kk = 0; kk < 4; ++kk) {
            acc[kk] += encp[k0 + kk][lane];
            float sm = acc[kk][0] + acc[kk][1] + acc[kk][2] + acc[kk][3];
            float sq = acc[kk][0]*acc[kk][0] + acc[kk][1]*acc[kk][1]
                     + acc[kk][2]*acc[kk][2] + acc[kk][3]*acc[kk][3];
            sm = wred_sum(sm); sq = wred_sum(sq);
            float u = sm * (1.f / NH);
            float var = sq * (1.f / NH) - u * u;
            float rstd = rsqrtf(var + EPS_LN);
            f32x4 o;
#pragma unroll
            for (int j = 0; j < 4; ++j) o[j] = w5[j] * (acc[kk][j] - u) * rstd + b5[j];
            *reinterpret_cast<f32x4*>(out + ((size_t)b * NK + k0 + kk) * NH + h0) = o;
        }
    }
}

extern "C" void kernel_launch(void* const* d_in, const int* in_sizes, int n_in,
                              void* d_out, int out_size, void* d_ws, size_t ws_size,
                              hipStream_t stream) {
    const float* z        = (const float*)d_in[0];
    const float* prot     = (const float*)d_in[1];
    const float* ln1w     = (const float*)d_in[2];
    const float* ln1b     = (const float*)d_in[3];
    const float* ln2w     = (const float*)d_in[4];
    const float* ln2b     = (const float*)d_in[5];
    const float* ln3w     = (const float*)d_in[6];
    const float* ln3b     = (const float*)d_in[7];
    const float* ln4w     = (const float*)d_in[8];
    const float* ln4b     = (const float*)d_in[9];
    const float* ln5w     = (const float*)d_in[10];
    const float* ln5b     = (const float*)d_in[11];
    const float* w_weight = (const float*)d_in[12];
    const float* w_bias   = (const float*)d_in[13];
    const float* b_prime  = (const float*)d_in[14];
    const float* alphas   = (const float*)d_in[15];
    const float* beta_in  = (const float*)d_in[16];
    const float* beta_lb  = (const float*)d_in[17];
    const int*   flag     = (const int*)d_in[18];
    float* out = (float*)d_out;

    char* ws = (char*)d_ws;
    float*          pn_div = (float*)(ws);                       // 16 KB
    float*          q      = (float*)(ws + 16384);               // 512 KB
    __hip_bfloat16* w_bf   = (__hip_bfloat16*)(ws + 540672);     // 128 KB
    float*          p_k_i  = (float*)(ws + 671744);              // 6.55 MB
    float*          scores = (float*)(ws + 7225344);             // 410 KB
    __hip_bfloat16* kt     = (__hip_bfloat16*)(ws + 7634944);    // 52.4 MB

    k_prep<<<577, 256, 0, stream>>>(prot, ln2w, ln2b, w_weight, w_bf,
                                    z, b_prime, alphas, ln4w, ln4b, pn_div, q);
    k_rows<<<NB * NS / 8, 256, 0, stream>>>(z, pn_div, ln1w, ln1b, ln3w, ln3b,
                                            alphas, q, p_k_i, kt, scores);
    k_gemm_scores<<<NB * NS / 64, 256, 0, stream>>>(kt, w_bf, w_bias, q, scores);
    k_final<<<NB, 512, 0, stream>>>(z, scores, p_k_i, beta_in, beta_lb, flag, ln5w, ln5b, out);
}

// Round 7
// 269.899 us; speedup vs baseline: 1.4695x; 1.1744x over previous
//
#include <hip/hip_runtime.h>
#include <hip/hip_bf16.h>

#define NB 512
#define NS 200
#define NK 16
#define NH 256
#define INV_SQRT_H 0.0625f
#define EPS_LN 1e-12f
#define EPS_COS 1e-6f
#define KTPAD 264   // shorts per LDS row: b128 starts spread mod 8 banks, <=2-way per 16-lane quarter

typedef __attribute__((ext_vector_type(8))) short bf16x8;
typedef __attribute__((ext_vector_type(4))) short s16x4;
typedef __attribute__((ext_vector_type(4))) float f32x4;

__device__ __forceinline__ float wred_sum(float v) {
    v += __shfl_xor(v, 1);  v += __shfl_xor(v, 2);  v += __shfl_xor(v, 4);
    v += __shfl_xor(v, 8);  v += __shfl_xor(v, 16); v += __shfl_xor(v, 32);
    return v;
}

__device__ __forceinline__ float red16(float v) {
    v += __shfl_xor(v, 1);  v += __shfl_xor(v, 2);
    v += __shfl_xor(v, 4);  v += __shfl_xor(v, 8);
    return v;
}

__device__ __forceinline__ float red32(float v) {
    v += __shfl_xor(v, 1);  v += __shfl_xor(v, 2);  v += __shfl_xor(v, 4);
    v += __shfl_xor(v, 8);  v += __shfl_xor(v, 16);
    return v;
}

__device__ __forceinline__ float block_sum256(float v, float* scr) {
    v = wred_sum(v);
    int w = threadIdx.x >> 6;
    __syncthreads();
    if ((threadIdx.x & 63) == 0) scr[w] = v;
    __syncthreads();
    return scr[0] + scr[1] + scr[2] + scr[3];
}

// ---------------- Kernel 1: protos -> ptil(bf16),A,B | cast W | query LN4 ----------------
__global__ __launch_bounds__(256) void k_prep(
        const float* __restrict__ prot, const float* __restrict__ w2, const float* __restrict__ b2,
        const float* __restrict__ ln1w, const float* __restrict__ ln1b,
        const float* __restrict__ w_weight, __hip_bfloat16* __restrict__ w_bf,
        const float* __restrict__ z, const float* __restrict__ b_prime,
        const float* __restrict__ alphas, const float* __restrict__ w4, const float* __restrict__ b4,
        __hip_bfloat16* __restrict__ ptil, float* __restrict__ Acst, float* __restrict__ Bcst,
        float* __restrict__ q) {
    __shared__ float scr[4];
    int t = threadIdx.x;
    int bid = blockIdx.x;
    if (bid == 0) {
        // one 16-lane group per prototype
        int c = t & 15, k = t >> 4;
        int h0 = c * 4;
        f32x4 x[4];
        float sm = 0.f, sq = 0.f;
#pragma unroll
        for (int j = 0; j < 4; ++j) {
            x[j] = *reinterpret_cast<const f32x4*>(prot + k * NH + h0 + 64 * j);
#pragma unroll
            for (int i = 0; i < 4; ++i) { sm += x[j][i]; sq += x[j][i] * x[j][i]; }
        }
        sm = red16(sm); sq = red16(sq);
        float u = sm * (1.f / NH);
        float var = sq * (1.f / NH) - u * u;
        float rstd = rsqrtf(var + EPS_LN);
        f32x4 pn[4];
        float nsq = 0.f;
#pragma unroll
        for (int j = 0; j < 4; ++j) {
            f32x4 wv = *reinterpret_cast<const f32x4*>(w2 + h0 + 64 * j);
            f32x4 bv = *reinterpret_cast<const f32x4*>(b2 + h0 + 64 * j);
#pragma unroll
            for (int i = 0; i < 4; ++i) {
                pn[j][i] = wv[i] * (x[j][i] - u) * rstd + bv[i];
                nsq += pn[j][i] * pn[j][i];
            }
        }
        nsq = red16(nsq);
        float pinv = 1.f / fmaxf(sqrtf(nsq), EPS_COS);
        // ptil[k][h] = ln1w[h] * pdiv[k][h] (bf16); A_k = sum ln1w*pdiv; B_k = sum ln1b*pdiv
        float asum = 0.f, bsum = 0.f;
#pragma unroll
        for (int j = 0; j < 4; ++j) {
            f32x4 w1 = *reinterpret_cast<const f32x4*>(ln1w + h0 + 64 * j);
            f32x4 b1 = *reinterpret_cast<const f32x4*>(ln1b + h0 + 64 * j);
            f32x4 o = pn[j] * pinv;
            union { s16x4 v; __hip_bfloat16 h[4]; } pt;
#pragma unroll
            for (int i = 0; i < 4; ++i) {
                pt.h[i] = __float2bfloat16(w1[i] * o[i]);
                asum += w1[i] * o[i];
                bsum += b1[i] * o[i];
            }
            *reinterpret_cast<s16x4*>(ptil + k * NH + h0 + 64 * j) = pt.v;
        }
        asum = red16(asum); bsum = red16(bsum);
        if (c == 0) { Acst[k] = asum; Bcst[k] = bsum; }
    } else if (bid <= 64) {
        int i = ((bid - 1) * 256 + t) * 4;
        f32x4 w = *reinterpret_cast<const f32x4*>(w_weight + i);
        union { s16x4 v; __hip_bfloat16 h[4]; } u;
#pragma unroll
        for (int j = 0; j < 4; ++j) u.h[j] = __float2bfloat16(w[j]);
        *reinterpret_cast<s16x4*>(w_bf + i) = u.v;
    } else {
        int b = bid - 65;
        float x = b_prime[t] + alphas[(NS - 1) * NH + t] + z[((size_t)b * NS + (NS - 1)) * NH + t];
        float u = block_sum256(x, scr) * (1.f / NH);
        float d = x - u;
        float var = block_sum256(d * d, scr) * (1.f / NH);
        q[b * NH + t] = w4[t] * d * rsqrtf(var + EPS_LN) + b4[t];
    }
}

// ---------------- Kernel 2: row stats + kt + ktq (phase 1), zp MFMA + softmax (phase 2) ----------------
// Block = 64 rows, 256 threads. Phase 1: 32 lanes/row, 8 rows/pass, 8 passes.
__global__ __launch_bounds__(256) void k_rows_mfma(
        const float* __restrict__ z,
        const float* __restrict__ ln1w, const float* __restrict__ ln1b,
        const float* __restrict__ ln3w, const float* __restrict__ ln3b,
        const float* __restrict__ alphas, const float* __restrict__ q,
        const __hip_bfloat16* __restrict__ ptil,
        const float* __restrict__ Acst, const float* __restrict__ Bcst,
        float* __restrict__ p_k_i, __hip_bfloat16* __restrict__ kt,
        float* __restrict__ scores) {
    __shared__ __hip_bfloat16 zbf[64 * KTPAD];   // 33.8 KB raw z in bf16
    __shared__ float zp[64 * 17];                // MFMA result transpose
    __shared__ float uu[64], rs[64], izn[64];
    __shared__ float Al[16], Bl[16];

    int tid = threadIdx.x;
    int c   = tid & 31;
    int grp = tid >> 5;
    int row0 = blockIdx.x * 64;
    int h0 = c * 8;

    if (tid < 16) { Al[tid] = Acst[tid]; Bl[tid] = Bcst[tid]; }

    // ---------------- Phase 1 ----------------
#pragma unroll 1
    for (int jr = 0; jr < 8; ++jr) {
        int rl  = grp + 8 * jr;
        int row = row0 + rl;
        int s   = row % NS;
        int b   = row / NS;
        size_t base = (size_t)row * NH;

        f32x4 zv0 = *reinterpret_cast<const f32x4*>(z + base + h0);
        f32x4 zv1 = *reinterpret_cast<const f32x4*>(z + base + h0 + 4);
        float sm = 0.f, sq = 0.f;
#pragma unroll
        for (int i = 0; i < 4; ++i) { sm += zv0[i] + zv1[i]; sq += zv0[i]*zv0[i] + zv1[i]*zv1[i]; }
        sm = red32(sm); sq = red32(sq);
        float u    = sm * (1.f / NH);
        float var  = sq * (1.f / NH) - u * u;
        float rstd = rsqrtf(var + EPS_LN);

        // zn only for ||zn||
        float nsq = 0.f;
        {
            f32x4 w1a = *reinterpret_cast<const f32x4*>(ln1w + h0);
            f32x4 w1b = *reinterpret_cast<const f32x4*>(ln1w + h0 + 4);
            f32x4 b1a = *reinterpret_cast<const f32x4*>(ln1b + h0);
            f32x4 b1b = *reinterpret_cast<const f32x4*>(ln1b + h0 + 4);
#pragma unroll
            for (int i = 0; i < 4; ++i) {
                float a = w1a[i] * (zv0[i] - u) * rstd + b1a[i];
                float d = w1b[i] * (zv1[i] - u) * rstd + b1b[i];
                nsq += a * a + d * d;
            }
        }
        nsq = red32(nsq);
        float izn_v = 1.f / fmaxf(sqrtf(nsq), EPS_COS);

        // stage raw z as bf16 for the zp GEMM
        {
            union { bf16x8 v; __hip_bfloat16 h[8]; } zc;
#pragma unroll
            for (int i = 0; i < 4; ++i) {
                zc.h[i]     = __float2bfloat16(zv0[i]);
                zc.h[i + 4] = __float2bfloat16(zv1[i]);
            }
            *reinterpret_cast<bf16x8*>(&zbf[rl * KTPAD + h0]) = zc.v;
        }

        // keys_tilde = LN3(z + alphas[s]) -> kt + ktq
        f32x4 xv0, xv1;
        {
            f32x4 aa = *reinterpret_cast<const f32x4*>(alphas + s * NH + h0);
            f32x4 ab = *reinterpret_cast<const f32x4*>(alphas + s * NH + h0 + 4);
            xv0 = zv0 + aa; xv1 = zv1 + ab;
        }
        float sm3 = 0.f, sq3 = 0.f;
#pragma unroll
        for (int i = 0; i < 4; ++i) { sm3 += xv0[i] + xv1[i]; sq3 += xv0[i]*xv0[i] + xv1[i]*xv1[i]; }
        sm3 = red32(sm3); sq3 = red32(sq3);
        float u3 = sm3 * (1.f / NH);
        float v3 = sq3 * (1.f / NH) - u3 * u3;
        float r3 = rsqrtf(v3 + EPS_LN);

        float ktq = 0.f;
        union { bf16x8 v; __hip_bfloat16 h[8]; } kv;
        {
            f32x4 w3a = *reinterpret_cast<const f32x4*>(ln3w + h0);
            f32x4 w3b = *reinterpret_cast<const f32x4*>(ln3w + h0 + 4);
            f32x4 b3a = *reinterpret_cast<const f32x4*>(ln3b + h0);
            f32x4 b3b = *reinterpret_cast<const f32x4*>(ln3b + h0 + 4);
            f32x4 qa  = *reinterpret_cast<const f32x4*>(q + b * NH + h0);
            f32x4 qb  = *reinterpret_cast<const f32x4*>(q + b * NH + h0 + 4);
#pragma unroll
            for (int i = 0; i < 4; ++i) {
                float k0 = w3a[i] * (xv0[i] - u3) * r3 + b3a[i];
                float k1 = w3b[i] * (xv1[i] - u3) * r3 + b3b[i];
                kv.h[i]     = __float2bfloat16(k0);
                kv.h[i + 4] = __float2bfloat16(k1);
                ktq += k0 * qa[i] + k1 * qb[i];
            }
        }
        *reinterpret_cast<bf16x8*>(kt + base + h0) = kv.v;
        ktq = red32(ktq);
        if (c == 0) {
            scores[row] = ktq;
            uu[rl] = u; rs[rl] = rstd; izn[rl] = izn_v;
        }
    }
    __syncthreads();

    // ---------------- Phase 2: zp = zbf @ ptil^T via MFMA (64x16, K=256) ----------------
    int wave = tid >> 6, lane = tid & 63;
    int m = lane & 15, g = lane >> 4;
    f32x4 acc = {0.f, 0.f, 0.f, 0.f};
#pragma unroll
    for (int ks = 0; ks < 8; ++ks) {
        bf16x8 a = *reinterpret_cast<const bf16x8*>(&zbf[(wave * 16 + m) * KTPAD + ks * 32 + g * 8]);
        bf16x8 bb = *reinterpret_cast<const bf16x8*>(ptil + m * NH + ks * 32 + g * 8);
        acc = __builtin_amdgcn_mfma_f32_16x16x32_bf16(a, bb, acc, 0, 0, 0);
    }
    // D[row = g*4+r][col=k=m] -> LDS transpose
#pragma unroll
    for (int r = 0; r < 4; ++r)
        zp[(wave * 16 + g * 4 + r) * 17 + m] = acc[r];
    __syncthreads();

    // per-row softmax over 16 protos, zero shuffles
    if (tid < 64) {
        float u = uu[tid], rstd = rs[tid], iz = izn[tid];
        float lg[NK];
        float mx = -1e30f;
#pragma unroll
        for (int k = 0; k < NK; ++k) {
            lg[k] = (rstd * (zp[tid * 17 + k] - u * Al[k]) + Bl[k]) * iz * INV_SQRT_H;
            mx = fmaxf(mx, lg[k]);
        }
        float se = 0.f;
#pragma unroll
        for (int k = 0; k < NK; ++k) { lg[k] = __expf(lg[k] - mx); se += lg[k]; }
        float inv = 1.f / se;
        float* dst = p_k_i + (size_t)(row0 + tid) * NK;
#pragma unroll
        for (int jj = 0; jj < 4; ++jj) {
            f32x4 o = { lg[4*jj] * inv, lg[4*jj+1] * inv, lg[4*jj+2] * inv, lg[4*jj+3] * inv };
            *reinterpret_cast<f32x4*>(dst + 4 * jj) = o;
        }
    }
}

// ---------------- Kernel 3: MFMA GEMM kt@W^T (A in LDS) + relu.q, LDS-transpose epilogue ----------------
__global__ __launch_bounds__(256) void k_gemm_scores(
        const __hip_bfloat16* __restrict__ kt, const __hip_bfloat16* __restrict__ w_bf,
        const float* __restrict__ w_bias, const float* __restrict__ q,
        float* __restrict__ scores) {
    __shared__ __hip_bfloat16 kt_lds[64 * KTPAD];   // 33.8 KB; reused as float rp[64][65] in epilogue
    __shared__ float sc[4][64];
    int tid = threadIdx.x, wave = tid >> 6, lane = tid & 63;
    int g = lane >> 4, cc = lane & 15;
    int row0 = blockIdx.x * 64;
    int n_base = wave * 64;

    // stage A tile
#pragma unroll
    for (int u = 0; u < 8; ++u) {
        int ci = u * 256 + tid;
        bf16x8 v = *reinterpret_cast<const bf16x8*>(kt + (size_t)row0 * NH + ci * 8);
        int r = ci >> 5;
        int col = (ci & 31) * 8;
        *reinterpret_cast<bf16x8*>(&kt_lds[r * KTPAD + col]) = v;
    }
    __syncthreads();

    f32x4 acc[4][4];
#pragma unroll
    for (int mf = 0; mf < 4; ++mf)
#pragma unroll
        for (int nf = 0; nf < 4; ++nf) { f32x4 zz = {0.f, 0.f, 0.f, 0.f}; acc[mf][nf] = zz; }

#pragma unroll
    for (int ks = 0; ks < 8; ++ks) {
        bf16x8 a[4], bb[4];
#pragma unroll
        for (int mf = 0; mf < 4; ++mf)
            a[mf] = *reinterpret_cast<const bf16x8*>(&kt_lds[(mf * 16 + cc) * KTPAD + ks * 32 + g * 8]);
#pragma unroll
        for (int nf = 0; nf < 4; ++nf)
            bb[nf] = *reinterpret_cast<const bf16x8*>(
                w_bf + (size_t)(n_base + nf * 16 + cc) * NH + ks * 32 + g * 8);
#pragma unroll
        for (int mf = 0; mf < 4; ++mf)
#pragma unroll
            for (int nf = 0; nf < 4; ++nf)
                acc[mf][nf] = __builtin_amdgcn_mfma_f32_16x16x32_bf16(a[mf], bb[nf], acc[mf][nf], 0, 0, 0);
    }

    // epilogue: part[mf][r] = sum_nf relu(acc + bias) * q   (VALU only)
    int b_lo = row0 / NS, b_hi = (row0 + 63) / NS;
    float q_lo[4], q_hi[4];
#pragma unroll
    for (int nf = 0; nf < 4; ++nf) {
        int n = n_base + nf * 16 + cc;
        q_lo[nf] = q[b_lo * NH + n];
        q_hi[nf] = q[b_hi * NH + n];
    }
    float part[4][4];
#pragma unroll
    for (int mf = 0; mf < 4; ++mf) {
#pragma unroll
        for (int r = 0; r < 4; ++r) {
            int row = row0 + mf * 16 + g * 4 + r;
            bool hi = (row / NS) != b_lo;
            float p = 0.f;
#pragma unroll
            for (int nf = 0; nf < 4; ++nf) {
                int n = n_base + nf * 16 + cc;
                float uval = acc[mf][nf][r] + w_bias[n];
                p += fmaxf(uval, 0.f) * (hi ? q_hi[nf] : q_lo[nf]);
            }
            part[mf][r] = p;
        }
    }
    __syncthreads();   // kt_lds reads done everywhere; safe to reuse as rp
    float* rp = (float*)kt_lds;   // rp[64][65]
#pragma unroll
    for (int mf = 0; mf < 4; ++mf)
#pragma unroll
        for (int r = 0; r < 4; ++r)
            rp[(mf * 16 + g * 4 + r) * 65 + wave * 16 + cc] = part[mf][r];
    __syncthreads();

    int rr = tid & 63, seg = tid >> 6;
    float ss = 0.f;
#pragma unroll
    for (int j = 0; j < 16; ++j) ss += rp[rr * 65 + seg * 16 + j];
    sc[seg][rr] = ss;
    __syncthreads();
    if (tid < 64)
        scores[row0 + tid] += sc[0][tid] + sc[1][tid] + sc[2][tid] + sc[3][tid];
}

// ---------------- Kernel 4: softmax over S, aggregate (8 waves: 4 k-groups x 2 s-halves), LN5 ----------------
__global__ __launch_bounds__(512) void k_final(
        const float* __restrict__ z, const float* __restrict__ scores,
        const float* __restrict__ p_k_i,
        const float* __restrict__ beta_in, const float* __restrict__ beta_lb,
        const int* __restrict__ flag,
        const float* __restrict__ ln5w, const float* __restrict__ ln5b,
        float* __restrict__ out) {
    __shared__ float p_i[NS];
    __shared__ f32x4 attn4[NS * 4];
    __shared__ f32x4 encp[NK][64];
    int tid = threadIdx.x, lane = tid & 63, wave = tid >> 6;
    int b = blockIdx.x;

    if (wave == 0) {
        float l[4]; float mx = -1e30f;
#pragma unroll
        for (int j = 0; j < 4; ++j) {
            int s = lane + 64 * j;
            l[j] = (s < NS) ? scores[b * NS + s] * INV_SQRT_H : -1e30f;
            mx = fmaxf(mx, l[j]);
        }
#pragma unroll
        for (int m = 1; m < 64; m <<= 1) mx = fmaxf(mx, __shfl_xor(mx, m));
        float ev[4]; float se = 0.f;
#pragma unroll
        for (int j = 0; j < 4; ++j) {
            int s = lane + 64 * j;
            ev[j] = (s < NS) ? __expf(l[j] - mx) : 0.f;
            se += ev[j];
        }
        se = wred_sum(se);
        float inv = 1.f / se;
#pragma unroll
        for (int j = 0; j < 4; ++j) {
            int s = lane + 64 * j;
            if (s < NS) p_i[s] = ev[j] * inv;
        }
    }
    __syncthreads();
    for (int idx = tid; idx < NS * 4; idx += 512) {
        f32x4 pk = *reinterpret_cast<const f32x4*>(p_k_i + (size_t)b * NS * NK + idx * 4);
        attn4[idx] = pk * p_i[idx >> 2];
    }
    __syncthreads();

    const float* beta = (*flag) ? beta_in : beta_lb;
    int kg = wave & 3;
    int sh = wave >> 2;
    int k0 = kg * 4;
    int h0 = lane * 4;
    f32x4 acc[4];
#pragma unroll
    for (int kk = 0; kk < 4; ++kk) {
        if (sh == 0)
            acc[kk] = *reinterpret_cast<const f32x4*>(beta + (k0 + kk) * NH + h0);
        else
            { f32x4 zz = {0.f,0.f,0.f,0.f}; acc[kk] = zz; }
    }

    const float* zb = z + (size_t)b * NS * NH + h0;
    int s0 = sh * 100;
    for (int s = s0; s < s0 + 100; s += 4) {
        f32x4 zv0 = *reinterpret_cast<const f32x4*>(zb + (s + 0) * NH);
        f32x4 zv1 = *reinterpret_cast<const f32x4*>(zb + (s + 1) * NH);
        f32x4 zv2 = *reinterpret_cast<const f32x4*>(zb + (s + 2) * NH);
        f32x4 zv3 = *reinterpret_cast<const f32x4*>(zb + (s + 3) * NH);
        f32x4 at0 = attn4[(s + 0) * 4 + kg];
        f32x4 at1 = attn4[(s + 1) * 4 + kg];
        f32x4 at2 = attn4[(s + 2) * 4 + kg];
        f32x4 at3 = attn4[(s + 3) * 4 + kg];
#pragma unroll
        for (int kk = 0; kk < 4; ++kk)
            acc[kk] += at0[kk] * zv0 + at1[kk] * zv1 + at2[kk] * zv2 + at3[kk] * zv3;
    }

    if (sh == 1) {
#pragma unroll
        for (int kk = 0; kk < 4; ++kk) encp[k0 + kk][lane] = acc[kk];
    }
    __syncthreads();
    if (sh == 0) {
        f32x4 w5 = *reinterpret_cast<const f32x4*>(ln5w + h0);
        f32x4 b5 = *reinterpret_cast<const f32x4*>(ln5b + h0);
#pragma unroll
        for (int kk = 0; kk < 4; ++kk) {
            acc[kk] += encp[k0 + kk][lane];
            float sm = acc[kk][0] + acc[kk][1] + acc[kk][2] + acc[kk][3];
            float sq = acc[kk][0]*acc[kk][0] + acc[kk][1]*acc[kk][1]
                     + acc[kk][2]*acc[kk][2] + acc[kk][3]*acc[kk][3];
            sm = wred_sum(sm); sq = wred_sum(sq);
            float u = sm * (1.f / NH);
            float var = sq * (1.f / NH) - u * u;
            float rstd = rsqrtf(var + EPS_LN);
            f32x4 o;
#pragma unroll
            for (int j = 0; j < 4; ++j) o[j] = w5[j] * (acc[kk][j] - u) * rstd + b5[j];
            *reinterpret_cast<f32x4*>(out + ((size_t)b * NK + k0 + kk) * NH + h0) = o;
        }
    }
}

extern "C" void kernel_launch(void* const* d_in, const int* in_sizes, int n_in,
                              void* d_out, int out_size, void* d_ws, size_t ws_size,
                              hipStream_t stream) {
    const float* z        = (const float*)d_in[0];
    const float* prot     = (const float*)d_in[1];
    const float* ln1w     = (const float*)d_in[2];
    const float* ln1b     = (const float*)d_in[3];
    const float* ln2w     = (const float*)d_in[4];
    const float* ln2b     = (const float*)d_in[5];
    const float* ln3w     = (const float*)d_in[6];
    const float* ln3b     = (const float*)d_in[7];
    const float* ln4w     = (const float*)d_in[8];
    const float* ln4b     = (const float*)d_in[9];
    const float* ln5w     = (const float*)d_in[10];
    const float* ln5b     = (const float*)d_in[11];
    const float* w_weight = (const float*)d_in[12];
    const float* w_bias   = (const float*)d_in[13];
    const float* b_prime  = (const float*)d_in[14];
    const float* alphas   = (const float*)d_in[15];
    const float* beta_in  = (const float*)d_in[16];
    const float* beta_lb  = (const float*)d_in[17];
    const int*   flag     = (const int*)d_in[18];
    float* out = (float*)d_out;

    char* ws = (char*)d_ws;
    __hip_bfloat16* ptil   = (__hip_bfloat16*)(ws);              // 8 KB (in old pn_div slot)
    float*          Acst   = (float*)(ws + 8192);                // 64 B
    float*          Bcst   = (float*)(ws + 8256);                // 64 B
    float*          q      = (float*)(ws + 16384);               // 512 KB
    __hip_bfloat16* w_bf   = (__hip_bfloat16*)(ws + 540672);     // 128 KB
    float*          p_k_i  = (float*)(ws + 671744);              // 6.55 MB
    float*          scores = (float*)(ws + 7225344);             // 410 KB
    __hip_bfloat16* kt     = (__hip_bfloat16*)(ws + 7634944);    // 52.4 MB

    k_prep<<<577, 256, 0, stream>>>(prot, ln2w, ln2b, ln1w, ln1b, w_weight, w_bf,
                                    z, b_prime, alphas, ln4w, ln4b, ptil, Acst, Bcst, q);
    k_rows_mfma<<<NB * NS / 64, 256, 0, stream>>>(z, ln1w, ln1b, ln3w, ln3b, alphas, q,
                                                  ptil, Acst, Bcst, p_k_i, kt, scores);
    k_gemm_scores<<<NB * NS / 64, 256, 0, stream>>>(kt, w_bf, w_bias, q, scores);
    k_final<<<NB, 512, 0, stream>>>(z, scores, p_k_i, beta_in, beta_lb, flag, ln5w, ln5b, out);
}